// Round 1
// 509.968 us; speedup vs baseline: 1.0161x; 1.0161x over previous
//
#include <hip/hip_runtime.h>
#include <hip/hip_bf16.h>

#define N_USERS   100000
#define N_ITEMS   50000
#define N_NODES_C 150000
#define EMB       64
#define N_ELEM    (N_NODES_C * EMB)   // 9,600,000
#define BKT_SHIFT 9
#define NBKT      ((N_NODES_C + 511) >> 9)              // 293
#define BKT_CAP   20480                                 // mean 16384 + 32 sigma
#define CH_EDGES  4096
#define EPT       16                                    // edges/thread, scatter_bucket

typedef unsigned int u32x4 __attribute__((ext_vector_type(4)));
typedef unsigned long long u64;

// ---- dtype detection (fp32 vs bf16-packed) + zero bucket tails ----
__global__ void detect_and_zero(const unsigned int* __restrict__ emb_u32,
                                const unsigned int* __restrict__ vals_u32,
                                int* __restrict__ flags,
                                int* __restrict__ tails) {
    int t = threadIdx.x;
    for (int b = t; b < NBKT; b += 256) tails[b] = 0;
    int cnt_emb = 0, cnt_vals = 0;
    for (int k = t; k < 1024; k += 256) {
        unsigned e = (emb_u32[k] >> 7) & 0xFFu;
        cnt_emb += (e >= 100u && e <= 127u) ? 1 : 0;
        cnt_vals += (vals_u32[k] >> 15) & 1u;
    }
    __shared__ int s0[256], s1[256];
    s0[t] = cnt_emb; s1[t] = cnt_vals;
    __syncthreads();
    for (int s = 128; s > 0; s >>= 1) {
        if (t < s) { s0[t] += s0[t + s]; s1[t] += s1[t + s]; }
        __syncthreads();
    }
    if (t == 0) {
        flags[0] = (s0[0] > 512) ? 1 : 0;   // emb/out bf16?
        flags[1] = (s1[0] > 100) ? 0 : 1;   // vals bf16?
    }
}

__device__ __forceinline__ float load_f(const void* base, size_t i, int is_bf16) {
    if (is_bf16) return __bfloat162float(((const __hip_bfloat16*)base)[i]);
    return ((const float*)base)[i];
}
__device__ __forceinline__ unsigned int bf16_bits(float f) {
    __hip_bfloat16 h = __float2bfloat16(f);
    return (unsigned int)reinterpret_cast<unsigned short&>(h);
}
__device__ __forceinline__ float lo_bf(unsigned int u) {
    return __uint_as_float(u << 16);
}
__device__ __forceinline__ float hi_bf(unsigned int u) {
    return __uint_as_float(u & 0xFFFF0000u);
}

// ---- init: h0 = ego (bf16). d_out untouched until the last spmm. ----
__global__ void init_kernel(const void* __restrict__ eu,
                            const void* __restrict__ ei,
                            __hip_bfloat16* __restrict__ h0,
                            const int* __restrict__ flags) {
    int i = blockIdx.x * blockDim.x + threadIdx.x;
    if (i >= N_ELEM) return;
    int ebf = flags[0];
    float f = (i < N_USERS * EMB) ? load_f(eu, i, ebf)
                                  : load_f(ei, i - N_USERS * EMB, ebf);
    h0[i] = __float2bfloat16(f);
}

// ---- bin edges into fixed-capacity buckets (packed u64), bulk tail claims ----
__global__ void scatter_bucket(const int* __restrict__ rows, const int* __restrict__ cols,
                               const void* __restrict__ vals,
                               u64* __restrict__ tmp,
                               int* __restrict__ tails, int nnz,
                               const int* __restrict__ flags) {
    __shared__ int lcnt[NBKT];
    __shared__ int lbase[NBKT];
    int t = threadIdx.x;
    for (int b = t; b < NBKT; b += 256) lcnt[b] = 0;
    __syncthreads();
    int base = blockIdx.x * CH_EDGES;
    int vbf = flags[1];
    u64 pk[EPT];
    unsigned int br[EPT];
    #pragma unroll
    for (int i = 0; i < EPT; ++i) {
        int e = base + i * 256 + t;
        if (e < nnz) {
            int r = rows[e];
            int c = cols[e];
            float v = load_f(vals, (size_t)e, vbf);
            int bk = r >> BKT_SHIFT;
            int rk = atomicAdd(&lcnt[bk], 1);
            pk[i] = ((u64)(unsigned)r << 34)
                  | ((u64)(unsigned)c << 16)
                  | (u64)bf16_bits(v);
            br[i] = ((unsigned)bk << 16) | (unsigned)rk;
        } else {
            br[i] = 0xFFFFFFFFu;
        }
    }
    __syncthreads();
    for (int b = t; b < NBKT; b += 256)
        lbase[b] = lcnt[b] ? atomicAdd(&tails[b], lcnt[b]) : 0;
    __syncthreads();
    #pragma unroll
    for (int i = 0; i < EPT; ++i) {
        if (br[i] != 0xFFFFFFFFu) {
            int bk = br[i] >> 16, rk = br[i] & 0xFFFFu;
            int pos = lbase[bk] + rk;
            if (pos < BKT_CAP)
                tmp[(size_t)bk * BKT_CAP + pos] = pk[i];
        }
    }
}

// ---- one block per bucket: per-block prefix over bucket counts (folded scan),
//      count rows, LDS scan -> row_ptr slice, scatter edges into CSR order.
//      Edge record: .x = c<<7 (byte offset into x), .y = bf16(v)<<16. ----
__global__ void bucket_csr(const u64* __restrict__ tmp,
                           int2* __restrict__ edges,
                           const int* __restrict__ tails,
                           int* __restrict__ row_ptr) {
    __shared__ int cnt[512];
    __shared__ int off[512];
    __shared__ int red[512];
    int b = blockIdx.x, t = threadIdx.x;
    // exclusive prefix of (clamped) tails over buckets < b
    int pre = 0;
    for (int i = t; i < b; i += 512) {
        int v = tails[i];
        pre += (v > BKT_CAP) ? BKT_CAP : v;
    }
    red[t] = pre;
    cnt[t] = 0;
    int rowbase = b << BKT_SHIFT;
    int nrows = N_NODES_C - rowbase; if (nrows > 512) nrows = 512;
    int n = tails[b];
    if (n > BKT_CAP) n = BKT_CAP;
    const u64* src = tmp + (size_t)b * BKT_CAP;
    __syncthreads();
    for (int st = 256; st > 0; st >>= 1) {
        if (t < st) red[t] += red[t + st];
        __syncthreads();
    }
    int obase = red[0];
    for (int e = t; e < n; e += 512)
        atomicAdd(&cnt[(int)(src[e] >> 34) - rowbase], 1);
    __syncthreads();
    int v = cnt[t];
    off[t] = v;
    __syncthreads();
    for (int o = 1; o < 512; o <<= 1) {
        int u = (t >= o) ? off[t - o] : 0;
        __syncthreads();
        off[t] += u;
        __syncthreads();
    }
    int excl = off[t] - v;
    __syncthreads();
    off[t] = obase + excl;
    if (t < nrows) row_ptr[rowbase + t] = obase + excl;
    if (b == NBKT - 1 && t == 0) row_ptr[N_NODES_C] = obase + n;
    __syncthreads();
    for (int e = t; e < n; e += 512) {
        u64 p = src[e];
        int rloc = (int)(p >> 34) - rowbase;
        unsigned c = (unsigned)((p >> 16) & 0x3FFFFu);
        int pos = atomicAdd(&off[rloc], 1);
        edges[pos] = make_int2((int)(c << 7), (int)((unsigned)(p & 0xFFFFu) << 16));
    }
}

// Pair two edges' x-words + weight pair into packed-bf16 dot2s.
// perm(a=S0 hi-bytes 4..7, b=S1 lo-bytes 0..3):
//  even elems {A.e0,B.e0}: sel 0x01000504 ; odd elems / v-pair: sel 0x03020706
#define DOT2Q(wA, wB, vp, ae, ao)                                              \
    {                                                                          \
        unsigned _xe = __builtin_amdgcn_perm((wA), (wB), 0x01000504u);         \
        unsigned _xo = __builtin_amdgcn_perm((wA), (wB), 0x03020706u);         \
        asm("v_dot2_f32_bf16 %0, %1, %2, %0" : "+v"(ae) : "v"(_xe), "v"(vp));  \
        asm("v_dot2_f32_bf16 %0, %1, %2, %0" : "+v"(ao) : "v"(_xo), "v"(vp));  \
    }

#define SWZ_ADD(a, pat) \
    a += __int_as_float(__builtin_amdgcn_ds_swizzle(__float_as_int(a), pat))

// ---- CSR SpMM: one wave/row, 8 edge-slots x uint4 (full 128B row per edge),
//      4 chains (32 edges in flight), chains paired into v_dot2_f32_bf16.
//      Scalarized row/beg/end (s_load + scalar loop), byte-offset gathers.
//      last==0: y = A*x (bf16).  last==1: d_out = (h0+h1+h2+A*x)/4. ----
__global__ void spmm8(const __hip_bfloat16* __restrict__ x,
                      __hip_bfloat16* __restrict__ y,
                      const u64* __restrict__ edges,
                      const int* __restrict__ row_ptr,
                      const __hip_bfloat16* __restrict__ h0,
                      const __hip_bfloat16* __restrict__ h1,
                      void* __restrict__ out,
                      const int* __restrict__ flags,
                      int last) {
    int row = __builtin_amdgcn_readfirstlane(blockIdx.x * 4 + (threadIdx.x >> 6));
    if (row >= N_NODES_C) return;
    int lane = threadIdx.x & 63;
    int slot = lane >> 3;       // edge slot 0..7
    int s    = lane & 7;        // elem octet: elems [8s, 8s+7]
    int beg = row_ptr[row], end = row_ptr[row + 1];
    const char* xb = (const char*)x;
    const char* eb = (const char*)edges;
    unsigned s16 = (unsigned)s << 4;
    unsigned eoff = ((unsigned)(beg + slot)) << 3;
    float a0 = 0.f, a1 = 0.f, a2 = 0.f, a3 = 0.f,
          a4 = 0.f, a5 = 0.f, a6 = 0.f, a7 = 0.f;
    for (int e = beg; e < end; e += 32, eoff += 256) {
        int rem = end - e;
        const u64* ep = (const u64*)(eb + eoff);
        u64 pA = (slot      < rem) ? __builtin_nontemporal_load(ep)      : 0ULL;
        u64 pB = (slot + 8  < rem) ? __builtin_nontemporal_load(ep + 8)  : 0ULL;
        u64 pC = (slot + 16 < rem) ? __builtin_nontemporal_load(ep + 16) : 0ULL;
        u64 pD = (slot + 24 < rem) ? __builtin_nontemporal_load(ep + 24) : 0ULL;
        unsigned oA = (unsigned)pA + s16;
        unsigned oB = (unsigned)pB + s16;
        unsigned oC = (unsigned)pC + s16;
        unsigned oD = (unsigned)pD + s16;
        const uint4 gA = *reinterpret_cast<const uint4*>(xb + oA);
        const uint4 gB = *reinterpret_cast<const uint4*>(xb + oB);
        const uint4 gC = *reinterpret_cast<const uint4*>(xb + oC);
        const uint4 gD = *reinterpret_cast<const uint4*>(xb + oD);
        unsigned vAB = __builtin_amdgcn_perm((unsigned)(pA >> 32),
                                             (unsigned)(pB >> 32), 0x03020706u);
        unsigned vCD = __builtin_amdgcn_perm((unsigned)(pC >> 32),
                                             (unsigned)(pD >> 32), 0x03020706u);
        DOT2Q(gA.x, gB.x, vAB, a0, a1);
        DOT2Q(gA.y, gB.y, vAB, a2, a3);
        DOT2Q(gA.z, gB.z, vAB, a4, a5);
        DOT2Q(gA.w, gB.w, vAB, a6, a7);
        DOT2Q(gC.x, gD.x, vCD, a0, a1);
        DOT2Q(gC.y, gD.y, vCD, a2, a3);
        DOT2Q(gC.z, gD.z, vCD, a4, a5);
        DOT2Q(gC.w, gD.w, vCD, a6, a7);
    }
    // butterfly over slots: xor8, xor16 via ds_swizzle; xor32 via shfl
    SWZ_ADD(a0, 0x201F); SWZ_ADD(a1, 0x201F); SWZ_ADD(a2, 0x201F); SWZ_ADD(a3, 0x201F);
    SWZ_ADD(a4, 0x201F); SWZ_ADD(a5, 0x201F); SWZ_ADD(a6, 0x201F); SWZ_ADD(a7, 0x201F);
    SWZ_ADD(a0, 0x401F); SWZ_ADD(a1, 0x401F); SWZ_ADD(a2, 0x401F); SWZ_ADD(a3, 0x401F);
    SWZ_ADD(a4, 0x401F); SWZ_ADD(a5, 0x401F); SWZ_ADD(a6, 0x401F); SWZ_ADD(a7, 0x401F);
    a0 += __shfl_xor(a0, 32, 64);
    a1 += __shfl_xor(a1, 32, 64);
    a2 += __shfl_xor(a2, 32, 64);
    a3 += __shfl_xor(a3, 32, 64);
    a4 += __shfl_xor(a4, 32, 64);
    a5 += __shfl_xor(a5, 32, 64);
    a6 += __shfl_xor(a6, 32, 64);
    a7 += __shfl_xor(a7, 32, 64);
    if (slot != 0) return;
    size_t base = ((size_t)row << 6) + (s << 3);
    if (!last) {
        unsigned q0, q1, q2, q3;
        asm("v_cvt_pk_bf16_f32 %0, %1, %2" : "=v"(q0) : "v"(a0), "v"(a1));
        asm("v_cvt_pk_bf16_f32 %0, %1, %2" : "=v"(q1) : "v"(a2), "v"(a3));
        asm("v_cvt_pk_bf16_f32 %0, %1, %2" : "=v"(q2) : "v"(a4), "v"(a5));
        asm("v_cvt_pk_bf16_f32 %0, %1, %2" : "=v"(q3) : "v"(a6), "v"(a7));
        u32x4 o; o.x = q0; o.y = q1; o.z = q2; o.w = q3;
        __builtin_nontemporal_store(o, reinterpret_cast<u32x4*>(y + base));
    } else {
        const uint4 r0 = *reinterpret_cast<const uint4*>(h0 + base);
        const uint4 r1 = *reinterpret_cast<const uint4*>(h1 + base);
        const uint4 r2 = *reinterpret_cast<const uint4*>(x + base);  // x == h2
        float f0 = (lo_bf(r0.x) + lo_bf(r1.x) + lo_bf(r2.x) + a0) * 0.25f;
        float f1 = (hi_bf(r0.x) + hi_bf(r1.x) + hi_bf(r2.x) + a1) * 0.25f;
        float f2 = (lo_bf(r0.y) + lo_bf(r1.y) + lo_bf(r2.y) + a2) * 0.25f;
        float f3 = (hi_bf(r0.y) + hi_bf(r1.y) + hi_bf(r2.y) + a3) * 0.25f;
        float f4 = (lo_bf(r0.z) + lo_bf(r1.z) + lo_bf(r2.z) + a4) * 0.25f;
        float f5 = (hi_bf(r0.z) + hi_bf(r1.z) + hi_bf(r2.z) + a5) * 0.25f;
        float f6 = (lo_bf(r0.w) + lo_bf(r1.w) + lo_bf(r2.w) + a6) * 0.25f;
        float f7 = (hi_bf(r0.w) + hi_bf(r1.w) + hi_bf(r2.w) + a7) * 0.25f;
        if (flags[0]) {
            unsigned q0, q1, q2, q3;
            asm("v_cvt_pk_bf16_f32 %0, %1, %2" : "=v"(q0) : "v"(f0), "v"(f1));
            asm("v_cvt_pk_bf16_f32 %0, %1, %2" : "=v"(q1) : "v"(f2), "v"(f3));
            asm("v_cvt_pk_bf16_f32 %0, %1, %2" : "=v"(q2) : "v"(f4), "v"(f5));
            asm("v_cvt_pk_bf16_f32 %0, %1, %2" : "=v"(q3) : "v"(f6), "v"(f7));
            u32x4 o; o.x = q0; o.y = q1; o.z = q2; o.w = q3;
            __builtin_nontemporal_store(
                o, reinterpret_cast<u32x4*>((__hip_bfloat16*)out + base));
        } else {
            float* op = (float*)out + base;
            u32x4 q0, q1;
            q0.x = __float_as_uint(f0); q0.y = __float_as_uint(f1);
            q0.z = __float_as_uint(f2); q0.w = __float_as_uint(f3);
            q1.x = __float_as_uint(f4); q1.y = __float_as_uint(f5);
            q1.z = __float_as_uint(f6); q1.w = __float_as_uint(f7);
            __builtin_nontemporal_store(q0, reinterpret_cast<u32x4*>(op));
            __builtin_nontemporal_store(q1, reinterpret_cast<u32x4*>(op + 4));
        }
    }
}

extern "C" void kernel_launch(void* const* d_in, const int* in_sizes, int n_in,
                              void* d_out, int out_size, void* d_ws, size_t ws_size,
                              hipStream_t stream) {
    const void* eu   = d_in[0];
    const void* ei   = d_in[1];
    const void* vals = d_in[2];
    const int*  rows = (const int*)d_in[3];
    const int*  cols = (const int*)d_in[4];
    const int nnz = in_sizes[2];

    // ws layout: h0..h2 (57.6MB) | edges (38.4MB) | tables | align8 tmp (48MB)
    __hip_bfloat16* h[3];
    h[0] = (__hip_bfloat16*)d_ws;
    h[1] = h[0] + N_ELEM;
    h[2] = h[1] + N_ELEM;
    int2* edges   = (int2*)(h[2] + N_ELEM);
    int* row_ptr  = (int*)(edges + nnz);                  // N_NODES_C + 1
    int* tails    = row_ptr + (N_NODES_C + 1);            // NBKT
    int* flags    = tails + NBKT;                         // 2
    char* pt = (char*)(flags + 2);
    u64* tmp = (u64*)(((uintptr_t)pt + 7) & ~(uintptr_t)7);  // NBKT*CAP u64

    detect_and_zero<<<1, 256, 0, stream>>>((const unsigned int*)eu,
                                           (const unsigned int*)vals, flags, tails);
    init_kernel<<<(N_ELEM + 255) / 256, 256, 0, stream>>>(eu, ei, h[0], flags);

    // CSR build: slot-bucket scatter -> per-bucket (prefix + CSR sort)
    int nchunks = (nnz + CH_EDGES - 1) / CH_EDGES;
    scatter_bucket<<<nchunks, 256, 0, stream>>>(rows, cols, vals, tmp, tails, nnz, flags);
    bucket_csr<<<NBKT, 512, 0, stream>>>(tmp, edges, tails, row_ptr);

    // layers: h0 -> h1 -> h2 -> (fused final) d_out
    int nsb = (N_NODES_C + 3) / 4;
    spmm8<<<nsb, 256, 0, stream>>>(h[0], h[1], (const u64*)edges, row_ptr,
                                   nullptr, nullptr, nullptr, flags, 0);
    spmm8<<<nsb, 256, 0, stream>>>(h[1], h[2], (const u64*)edges, row_ptr,
                                   nullptr, nullptr, nullptr, flags, 0);
    spmm8<<<nsb, 256, 0, stream>>>(h[2], nullptr, (const u64*)edges, row_ptr,
                                   h[0], h[1], d_out, flags, 1);
}

// Round 2
// 499.595 us; speedup vs baseline: 1.0372x; 1.0208x over previous
//
#include <hip/hip_runtime.h>
#include <hip/hip_bf16.h>

#define N_USERS   100000
#define N_ITEMS   50000
#define N_NODES_C 150000
#define EMB       64
#define N_ELEM    (N_NODES_C * EMB)   // 9,600,000
#define BKT_SHIFT 9
#define NBKT      ((N_NODES_C + 511) >> 9)              // 293
#define BKT_CAP   20480                                 // mean 16384 + 32 sigma
#define CH_EDGES  4096
#define EPT       16                                    // edges/thread, scatter_bucket

typedef unsigned int u32x4 __attribute__((ext_vector_type(4)));
typedef unsigned int u32x2 __attribute__((ext_vector_type(2)));
typedef unsigned long long u64;

// ---- dtype detection (fp32 vs bf16-packed) + zero bucket tails ----
__global__ void detect_and_zero(const unsigned int* __restrict__ emb_u32,
                                const unsigned int* __restrict__ vals_u32,
                                int* __restrict__ flags,
                                int* __restrict__ tails) {
    int t = threadIdx.x;
    for (int b = t; b < NBKT; b += 256) tails[b] = 0;
    int cnt_emb = 0, cnt_vals = 0;
    for (int k = t; k < 1024; k += 256) {
        unsigned e = (emb_u32[k] >> 7) & 0xFFu;
        cnt_emb += (e >= 100u && e <= 127u) ? 1 : 0;
        cnt_vals += (vals_u32[k] >> 15) & 1u;
    }
    __shared__ int s0[256], s1[256];
    s0[t] = cnt_emb; s1[t] = cnt_vals;
    __syncthreads();
    for (int s = 128; s > 0; s >>= 1) {
        if (t < s) { s0[t] += s0[t + s]; s1[t] += s1[t + s]; }
        __syncthreads();
    }
    if (t == 0) {
        flags[0] = (s0[0] > 512) ? 1 : 0;   // emb/out bf16?
        flags[1] = (s1[0] > 100) ? 0 : 1;   // vals bf16?
    }
}

__device__ __forceinline__ float load_f(const void* base, size_t i, int is_bf16) {
    if (is_bf16) return __bfloat162float(((const __hip_bfloat16*)base)[i]);
    return ((const float*)base)[i];
}
__device__ __forceinline__ unsigned int bf16_bits(float f) {
    __hip_bfloat16 h = __float2bfloat16(f);
    return (unsigned int)reinterpret_cast<unsigned short&>(h);
}
__device__ __forceinline__ float lo_bf(unsigned int u) {
    return __uint_as_float(u << 16);
}
__device__ __forceinline__ float hi_bf(unsigned int u) {
    return __uint_as_float(u & 0xFFFF0000u);
}

// ---- init: h0 = ego (bf16), 4 elems/thread. ----
__global__ void init_kernel(const void* __restrict__ eu,
                            const void* __restrict__ ei,
                            __hip_bfloat16* __restrict__ h0,
                            const int* __restrict__ flags) {
    int q = blockIdx.x * blockDim.x + threadIdx.x;      // quad index
    if (q >= (N_ELEM >> 2)) return;
    int ebf = flags[0];
    const int uquads = (N_USERS * EMB) >> 2;
    u32x2 o;
    if (ebf) {
        // bf16 input: pure copy of 4 elems (8 B)
        o = (q < uquads)
              ? *((const u32x2*)eu + q)
              : *((const u32x2*)ei + (q - uquads));
    } else {
        const uint4 f = (q < uquads)
              ? *((const uint4*)eu + q)
              : *((const uint4*)ei + (q - uquads));
        unsigned r0, r1;
        asm("v_cvt_pk_bf16_f32 %0, %1, %2" : "=v"(r0)
            : "v"(__uint_as_float(f.x)), "v"(__uint_as_float(f.y)));
        asm("v_cvt_pk_bf16_f32 %0, %1, %2" : "=v"(r1)
            : "v"(__uint_as_float(f.z)), "v"(__uint_as_float(f.w)));
        o.x = r0; o.y = r1;
    }
    *reinterpret_cast<u32x2*>(h0 + ((size_t)q << 2)) = o;
}

// ---- bin edges into fixed-capacity buckets (packed u64), bulk tail claims ----
__global__ void scatter_bucket(const int* __restrict__ rows, const int* __restrict__ cols,
                               const void* __restrict__ vals,
                               u64* __restrict__ tmp,
                               int* __restrict__ tails, int nnz,
                               const int* __restrict__ flags) {
    __shared__ int lcnt[NBKT];
    __shared__ int lbase[NBKT];
    int t = threadIdx.x;
    for (int b = t; b < NBKT; b += 256) lcnt[b] = 0;
    __syncthreads();
    int base = blockIdx.x * CH_EDGES;
    int vbf = flags[1];
    u64 pk[EPT];
    unsigned int br[EPT];
    #pragma unroll
    for (int i = 0; i < EPT; ++i) {
        int e = base + i * 256 + t;
        if (e < nnz) {
            int r = rows[e];
            int c = cols[e];
            float v = load_f(vals, (size_t)e, vbf);
            int bk = r >> BKT_SHIFT;
            int rk = atomicAdd(&lcnt[bk], 1);
            pk[i] = ((u64)(unsigned)r << 34)
                  | ((u64)(unsigned)c << 16)
                  | (u64)bf16_bits(v);
            br[i] = ((unsigned)bk << 16) | (unsigned)rk;
        } else {
            br[i] = 0xFFFFFFFFu;
        }
    }
    __syncthreads();
    for (int b = t; b < NBKT; b += 256)
        lbase[b] = lcnt[b] ? atomicAdd(&tails[b], lcnt[b]) : 0;
    __syncthreads();
    #pragma unroll
    for (int i = 0; i < EPT; ++i) {
        if (br[i] != 0xFFFFFFFFu) {
            int bk = br[i] >> 16, rk = br[i] & 0xFFFFu;
            int pos = lbase[bk] + rk;
            if (pos < BKT_CAP)
                tmp[(size_t)bk * BKT_CAP + pos] = pk[i];
        }
    }
}

// ---- one block per bucket: per-block prefix over bucket counts (folded scan),
//      count rows, LDS scan -> row_ptr slice, scatter edges into CSR order.
//      Edge record: .x = c<<7 (byte offset into x), .y = bf16(v)<<16. ----
__global__ void bucket_csr(const u64* __restrict__ tmp,
                           int2* __restrict__ edges,
                           const int* __restrict__ tails,
                           int* __restrict__ row_ptr) {
    __shared__ int cnt[512];
    __shared__ int off[512];
    __shared__ int red[512];
    int b = blockIdx.x, t = threadIdx.x;
    // exclusive prefix of (clamped) tails over buckets < b
    int pre = 0;
    for (int i = t; i < b; i += 512) {
        int v = tails[i];
        pre += (v > BKT_CAP) ? BKT_CAP : v;
    }
    red[t] = pre;
    cnt[t] = 0;
    int rowbase = b << BKT_SHIFT;
    int nrows = N_NODES_C - rowbase; if (nrows > 512) nrows = 512;
    int n = tails[b];
    if (n > BKT_CAP) n = BKT_CAP;
    const u64* src = tmp + (size_t)b * BKT_CAP;
    __syncthreads();
    for (int st = 256; st > 0; st >>= 1) {
        if (t < st) red[t] += red[t + st];
        __syncthreads();
    }
    int obase = red[0];
    for (int e = t; e < n; e += 512)
        atomicAdd(&cnt[(int)(src[e] >> 34) - rowbase], 1);
    __syncthreads();
    int v = cnt[t];
    off[t] = v;
    __syncthreads();
    for (int o = 1; o < 512; o <<= 1) {
        int u = (t >= o) ? off[t - o] : 0;
        __syncthreads();
        off[t] += u;
        __syncthreads();
    }
    int excl = off[t] - v;
    __syncthreads();
    off[t] = obase + excl;
    if (t < nrows) row_ptr[rowbase + t] = obase + excl;
    if (b == NBKT - 1 && t == 0) row_ptr[N_NODES_C] = obase + n;
    __syncthreads();
    for (int e = t; e < n; e += 512) {
        u64 p = src[e];
        int rloc = (int)(p >> 34) - rowbase;
        unsigned c = (unsigned)((p >> 16) & 0x3FFFFu);
        int pos = atomicAdd(&off[rloc], 1);
        edges[pos] = make_int2((int)(c << 7), (int)((unsigned)(p & 0xFFFFu) << 16));
    }
}

// Pair two edges' x-words + weight pair into packed-bf16 dot2s.
#define DOT2Q(wA, wB, vp, ae, ao)                                              \
    {                                                                          \
        unsigned _xe = __builtin_amdgcn_perm((wA), (wB), 0x01000504u);         \
        unsigned _xo = __builtin_amdgcn_perm((wA), (wB), 0x03020706u);         \
        asm("v_dot2_f32_bf16 %0, %1, %2, %0" : "+v"(ae) : "v"(_xe), "v"(vp));  \
        asm("v_dot2_f32_bf16 %0, %1, %2, %0" : "+v"(ao) : "v"(_xo), "v"(vp));  \
    }

#define SWZ_ADD(a, pat) \
    a += __int_as_float(__builtin_amdgcn_ds_swizzle(__float_as_int(a), pat))

// ---- CSR SpMM: one wave/row, 8 edge-slots x uint4 (full 128B row per edge),
//      8 chains (64 edges in flight -> P(deg>64)~0: one iteration per row).
//      Chains paired into v_dot2_f32_bf16; byte-offset gathers.
//      last==0: y = A*x (bf16).  last==1: d_out = (h0+h1+h2+A*x)/4. ----
__global__ void spmm8(const __hip_bfloat16* __restrict__ x,
                      __hip_bfloat16* __restrict__ y,
                      const u64* __restrict__ edges,
                      const int* __restrict__ row_ptr,
                      const __hip_bfloat16* __restrict__ h0,
                      const __hip_bfloat16* __restrict__ h1,
                      void* __restrict__ out,
                      const int* __restrict__ flags,
                      int last) {
    int row = __builtin_amdgcn_readfirstlane(blockIdx.x * 4 + (threadIdx.x >> 6));
    if (row >= N_NODES_C) return;
    int lane = threadIdx.x & 63;
    int slot = lane >> 3;       // edge slot 0..7
    int s    = lane & 7;        // elem octet: elems [8s, 8s+7]
    int beg = row_ptr[row], end = row_ptr[row + 1];
    const char* xb = (const char*)x;
    const char* eb = (const char*)edges;
    unsigned s16 = (unsigned)s << 4;
    unsigned eoff = ((unsigned)(beg + slot)) << 3;
    float a0 = 0.f, a1 = 0.f, a2 = 0.f, a3 = 0.f,
          a4 = 0.f, a5 = 0.f, a6 = 0.f, a7 = 0.f;
    for (int e = beg; e < end; e += 64, eoff += 512) {
        int rem = end - e;
        const u64* ep = (const u64*)(eb + eoff);
        u64 p0 = (slot      < rem) ? __builtin_nontemporal_load(ep)      : 0ULL;
        u64 p1 = (slot + 8  < rem) ? __builtin_nontemporal_load(ep + 8)  : 0ULL;
        u64 p2 = (slot + 16 < rem) ? __builtin_nontemporal_load(ep + 16) : 0ULL;
        u64 p3 = (slot + 24 < rem) ? __builtin_nontemporal_load(ep + 24) : 0ULL;
        u64 p4 = (slot + 32 < rem) ? __builtin_nontemporal_load(ep + 32) : 0ULL;
        u64 p5 = (slot + 40 < rem) ? __builtin_nontemporal_load(ep + 40) : 0ULL;
        u64 p6 = (slot + 48 < rem) ? __builtin_nontemporal_load(ep + 48) : 0ULL;
        u64 p7 = (slot + 56 < rem) ? __builtin_nontemporal_load(ep + 56) : 0ULL;
        unsigned o0 = (unsigned)p0 + s16;
        unsigned o1 = (unsigned)p1 + s16;
        unsigned o2 = (unsigned)p2 + s16;
        unsigned o3 = (unsigned)p3 + s16;
        unsigned o4 = (unsigned)p4 + s16;
        unsigned o5 = (unsigned)p5 + s16;
        unsigned o6 = (unsigned)p6 + s16;
        unsigned o7 = (unsigned)p7 + s16;
        const uint4 g0 = *reinterpret_cast<const uint4*>(xb + o0);
        const uint4 g1 = *reinterpret_cast<const uint4*>(xb + o1);
        const uint4 g2 = *reinterpret_cast<const uint4*>(xb + o2);
        const uint4 g3 = *reinterpret_cast<const uint4*>(xb + o3);
        const uint4 g4 = *reinterpret_cast<const uint4*>(xb + o4);
        const uint4 g5 = *reinterpret_cast<const uint4*>(xb + o5);
        const uint4 g6 = *reinterpret_cast<const uint4*>(xb + o6);
        const uint4 g7 = *reinterpret_cast<const uint4*>(xb + o7);
        unsigned v01 = __builtin_amdgcn_perm((unsigned)(p0 >> 32),
                                             (unsigned)(p1 >> 32), 0x03020706u);
        unsigned v23 = __builtin_amdgcn_perm((unsigned)(p2 >> 32),
                                             (unsigned)(p3 >> 32), 0x03020706u);
        unsigned v45 = __builtin_amdgcn_perm((unsigned)(p4 >> 32),
                                             (unsigned)(p5 >> 32), 0x03020706u);
        unsigned v67 = __builtin_amdgcn_perm((unsigned)(p6 >> 32),
                                             (unsigned)(p7 >> 32), 0x03020706u);
        DOT2Q(g0.x, g1.x, v01, a0, a1);
        DOT2Q(g0.y, g1.y, v01, a2, a3);
        DOT2Q(g0.z, g1.z, v01, a4, a5);
        DOT2Q(g0.w, g1.w, v01, a6, a7);
        DOT2Q(g2.x, g3.x, v23, a0, a1);
        DOT2Q(g2.y, g3.y, v23, a2, a3);
        DOT2Q(g2.z, g3.z, v23, a4, a5);
        DOT2Q(g2.w, g3.w, v23, a6, a7);
        DOT2Q(g4.x, g5.x, v45, a0, a1);
        DOT2Q(g4.y, g5.y, v45, a2, a3);
        DOT2Q(g4.z, g5.z, v45, a4, a5);
        DOT2Q(g4.w, g5.w, v45, a6, a7);
        DOT2Q(g6.x, g7.x, v67, a0, a1);
        DOT2Q(g6.y, g7.y, v67, a2, a3);
        DOT2Q(g6.z, g7.z, v67, a4, a5);
        DOT2Q(g6.w, g7.w, v67, a6, a7);
    }
    // butterfly over slots: xor8, xor16 via ds_swizzle; xor32 via shfl
    SWZ_ADD(a0, 0x201F); SWZ_ADD(a1, 0x201F); SWZ_ADD(a2, 0x201F); SWZ_ADD(a3, 0x201F);
    SWZ_ADD(a4, 0x201F); SWZ_ADD(a5, 0x201F); SWZ_ADD(a6, 0x201F); SWZ_ADD(a7, 0x201F);
    SWZ_ADD(a0, 0x401F); SWZ_ADD(a1, 0x401F); SWZ_ADD(a2, 0x401F); SWZ_ADD(a3, 0x401F);
    SWZ_ADD(a4, 0x401F); SWZ_ADD(a5, 0x401F); SWZ_ADD(a6, 0x401F); SWZ_ADD(a7, 0x401F);
    a0 += __shfl_xor(a0, 32, 64);
    a1 += __shfl_xor(a1, 32, 64);
    a2 += __shfl_xor(a2, 32, 64);
    a3 += __shfl_xor(a3, 32, 64);
    a4 += __shfl_xor(a4, 32, 64);
    a5 += __shfl_xor(a5, 32, 64);
    a6 += __shfl_xor(a6, 32, 64);
    a7 += __shfl_xor(a7, 32, 64);
    if (slot != 0) return;
    size_t base = ((size_t)row << 6) + (s << 3);
    if (!last) {
        unsigned q0, q1, q2, q3;
        asm("v_cvt_pk_bf16_f32 %0, %1, %2" : "=v"(q0) : "v"(a0), "v"(a1));
        asm("v_cvt_pk_bf16_f32 %0, %1, %2" : "=v"(q1) : "v"(a2), "v"(a3));
        asm("v_cvt_pk_bf16_f32 %0, %1, %2" : "=v"(q2) : "v"(a4), "v"(a5));
        asm("v_cvt_pk_bf16_f32 %0, %1, %2" : "=v"(q3) : "v"(a6), "v"(a7));
        u32x4 o; o.x = q0; o.y = q1; o.z = q2; o.w = q3;
        __builtin_nontemporal_store(o, reinterpret_cast<u32x4*>(y + base));
    } else {
        const uint4 r0 = *reinterpret_cast<const uint4*>(h0 + base);
        const uint4 r1 = *reinterpret_cast<const uint4*>(h1 + base);
        const uint4 r2 = *reinterpret_cast<const uint4*>(x + base);  // x == h2
        float f0 = (lo_bf(r0.x) + lo_bf(r1.x) + lo_bf(r2.x) + a0) * 0.25f;
        float f1 = (hi_bf(r0.x) + hi_bf(r1.x) + hi_bf(r2.x) + a1) * 0.25f;
        float f2 = (lo_bf(r0.y) + lo_bf(r1.y) + lo_bf(r2.y) + a2) * 0.25f;
        float f3 = (hi_bf(r0.y) + hi_bf(r1.y) + hi_bf(r2.y) + a3) * 0.25f;
        float f4 = (lo_bf(r0.z) + lo_bf(r1.z) + lo_bf(r2.z) + a4) * 0.25f;
        float f5 = (hi_bf(r0.z) + hi_bf(r1.z) + hi_bf(r2.z) + a5) * 0.25f;
        float f6 = (lo_bf(r0.w) + lo_bf(r1.w) + lo_bf(r2.w) + a6) * 0.25f;
        float f7 = (hi_bf(r0.w) + hi_bf(r1.w) + hi_bf(r2.w) + a7) * 0.25f;
        if (flags[0]) {
            unsigned q0, q1, q2, q3;
            asm("v_cvt_pk_bf16_f32 %0, %1, %2" : "=v"(q0) : "v"(f0), "v"(f1));
            asm("v_cvt_pk_bf16_f32 %0, %1, %2" : "=v"(q1) : "v"(f2), "v"(f3));
            asm("v_cvt_pk_bf16_f32 %0, %1, %2" : "=v"(q2) : "v"(f4), "v"(f5));
            asm("v_cvt_pk_bf16_f32 %0, %1, %2" : "=v"(q3) : "v"(f6), "v"(f7));
            u32x4 o; o.x = q0; o.y = q1; o.z = q2; o.w = q3;
            __builtin_nontemporal_store(
                o, reinterpret_cast<u32x4*>((__hip_bfloat16*)out + base));
        } else {
            float* op = (float*)out + base;
            u32x4 q0, q1;
            q0.x = __float_as_uint(f0); q0.y = __float_as_uint(f1);
            q0.z = __float_as_uint(f2); q0.w = __float_as_uint(f3);
            q1.x = __float_as_uint(f4); q1.y = __float_as_uint(f5);
            q1.z = __float_as_uint(f6); q1.w = __float_as_uint(f7);
            __builtin_nontemporal_store(q0, reinterpret_cast<u32x4*>(op));
            __builtin_nontemporal_store(q1, reinterpret_cast<u32x4*>(op + 4));
        }
    }
}

extern "C" void kernel_launch(void* const* d_in, const int* in_sizes, int n_in,
                              void* d_out, int out_size, void* d_ws, size_t ws_size,
                              hipStream_t stream) {
    const void* eu   = d_in[0];
    const void* ei   = d_in[1];
    const void* vals = d_in[2];
    const int*  rows = (const int*)d_in[3];
    const int*  cols = (const int*)d_in[4];
    const int nnz = in_sizes[2];

    // ws layout: h0..h2 (57.6MB) | edges (38.4MB) | tables | align8 tmp (48MB)
    __hip_bfloat16* h[3];
    h[0] = (__hip_bfloat16*)d_ws;
    h[1] = h[0] + N_ELEM;
    h[2] = h[1] + N_ELEM;
    int2* edges   = (int2*)(h[2] + N_ELEM);
    int* row_ptr  = (int*)(edges + nnz);                  // N_NODES_C + 1
    int* tails    = row_ptr + (N_NODES_C + 1);            // NBKT
    int* flags    = tails + NBKT;                         // 2
    char* pt = (char*)(flags + 2);
    u64* tmp = (u64*)(((uintptr_t)pt + 7) & ~(uintptr_t)7);  // NBKT*CAP u64

    detect_and_zero<<<1, 256, 0, stream>>>((const unsigned int*)eu,
                                           (const unsigned int*)vals, flags, tails);
    init_kernel<<<((N_ELEM >> 2) + 255) / 256, 256, 0, stream>>>(eu, ei, h[0], flags);

    // CSR build: slot-bucket scatter -> per-bucket (prefix + CSR sort)
    int nchunks = (nnz + CH_EDGES - 1) / CH_EDGES;
    scatter_bucket<<<nchunks, 256, 0, stream>>>(rows, cols, vals, tmp, tails, nnz, flags);
    bucket_csr<<<NBKT, 512, 0, stream>>>(tmp, edges, tails, row_ptr);

    // layers: h0 -> h1 -> h2 -> (fused final) d_out
    int nsb = (N_NODES_C + 3) / 4;
    spmm8<<<nsb, 256, 0, stream>>>(h[0], h[1], (const u64*)edges, row_ptr,
                                   nullptr, nullptr, nullptr, flags, 0);
    spmm8<<<nsb, 256, 0, stream>>>(h[1], h[2], (const u64*)edges, row_ptr,
                                   nullptr, nullptr, nullptr, flags, 0);
    spmm8<<<nsb, 256, 0, stream>>>(h[2], nullptr, (const u64*)edges, row_ptr,
                                   h[0], h[1], d_out, flags, 1);
}